// Round 10
// baseline (566.980 us; speedup 1.0000x reference)
//
#include <hip/hip_runtime.h>

// GAT layer, N=8192, F_IN=512, F_OUT=256. ALL tensors f32; adj int32.
// out = softmax_row(mask(leaky(s1_i+s2_j))) @ h, h = X@W, s{1,2} = h_f32@a{1,2}.
//
// R19 -> R20:
//  * R19 killed the B-volume law (halved B bytes, got slower; VGPR=96, no
//    spill). All variants: ~3400 stall cyc/body vs ~600 work cyc, pipes idle.
//  * Remaining theory: per-wave load-latency under-coverage. Both waves/SIMD
//    are in ONE lockstep barrier group -> latency must be hidden in-register.
//    B was only 1 body ahead (R15); adj/s2 already 4 ahead.
//  * R20 = R15 verbatim + B ring-of-4: body j consumes B[j&3], ISSUES
//    loadB(j+2) -> 2 full bodies of flight. Static x4 unroll. +64 VGPR
//    (96 -> ~160, occupancy unchanged: grid-limited 1 block/CU).
//  * Traffic, numerics, LDS, barriers all unchanged -> absmax 0.0078125 canary.

typedef __attribute__((ext_vector_type(8))) short bf16x8;
typedef __attribute__((ext_vector_type(4))) float fx4;
typedef __attribute__((ext_vector_type(4))) int ix4;
typedef __attribute__((ext_vector_type(2))) unsigned int ux2;

#define NN 8192
#define FIN 512
#define FOUT 256
#define PS 136     // LDS P row stride (shorts); 272B stride -> conflict-free b128
#define AROWS 32   // attn rows per block

__device__ __forceinline__ unsigned short f2bf(float f) {
    unsigned int x = __float_as_uint(f);
    x += 0x7fffu + ((x >> 16) & 1u);
    return (unsigned short)(x >> 16);
}
__device__ __forceinline__ bf16x8 pack8(fx4 a, fx4 b) {
    bf16x8 r;
    r[0] = (short)f2bf(a[0]); r[1] = (short)f2bf(a[1]);
    r[2] = (short)f2bf(a[2]); r[3] = (short)f2bf(a[3]);
    r[4] = (short)f2bf(b[0]); r[5] = (short)f2bf(b[1]);
    r[6] = (short)f2bf(b[2]); r[7] = (short)f2bf(b[3]);
    return r;
}

// ---------- kernel 0: WTt[((k>>5)*256+c)*32 + (k&31)] = bf16(W[k][c]) ----------
__global__ void wt_kernel(const float* __restrict__ W,
                          unsigned short* __restrict__ WTt) {
    const int c = threadIdx.x;
    const int k = blockIdx.x;
    WTt[((size_t)(k >> 5) * 256 + c) * 32 + (k & 31)] = f2bf(W[k * FOUT + c]);
}

// ---------- kernel 1: h-tile (MFMA) + fused s1/s2 ----------
__global__ __launch_bounds__(256) void prep_kernel(
    const float* __restrict__ X,              // 8192x512 f32
    const unsigned short* __restrict__ WTt,   // tiled 256x512 bf16
    const float* __restrict__ A,              // 512 f32 (a1|a2)
    unsigned short* __restrict__ hTt,         // tiled 256x8192 bf16
    float* __restrict__ s1, float* __restrict__ s2)
{
    __shared__ float s1sh[4][16], s2sh[4][16];
    const int tid = threadIdx.x;

    const int w = tid >> 6, l = tid & 63, q = l >> 4, lr = l & 15;
    const int r0 = blockIdx.x * 16;
    const int cbase = w * 64;
    fx4 acc[4] = {};

    for (int kb = 0; kb < FIN; kb += 32) {
        const float* xp = X + (size_t)(r0 + lr) * FIN + kb + q * 8;
        bf16x8 a0 = pack8(*(const fx4*)xp, *(const fx4*)(xp + 4));
#pragma unroll
        for (int tc = 0; tc < 4; ++tc) {
            bf16x8 b = *(const bf16x8*)(WTt + ((size_t)(kb >> 5) * 256 + cbase + tc * 16 + lr) * 32 + q * 8);
            acc[tc] = __builtin_amdgcn_mfma_f32_16x16x32_bf16(a0, b, acc[tc], 0, 0, 0);
        }
    }

    // tiled hTt write
    const int jb = r0 >> 5, jo = (r0 & 31) + q * 4;
#pragma unroll
    for (int tc = 0; tc < 4; ++tc) {
        const int c = cbase + tc * 16 + lr;
        ux2 hp;
        hp.x = (unsigned)f2bf(acc[tc][0]) | ((unsigned)f2bf(acc[tc][1]) << 16);
        hp.y = (unsigned)f2bf(acc[tc][2]) | ((unsigned)f2bf(acc[tc][3]) << 16);
        *(ux2*)(hTt + ((size_t)jb * 256 + c) * 32 + jo) = hp;
    }

    // fused s1/s2 from f32 accumulators
    float p1[4] = {}, p2[4] = {};
#pragma unroll
    for (int tc = 0; tc < 4; ++tc) {
        const int c = cbase + tc * 16 + lr;
        const float a1v = A[c], a2v = A[FOUT + c];
#pragma unroll
        for (int r = 0; r < 4; ++r) {
            p1[r] += acc[tc][r] * a1v;
            p2[r] += acc[tc][r] * a2v;
        }
    }
#pragma unroll
    for (int r = 0; r < 4; ++r) {
#pragma unroll
        for (int off = 1; off < 16; off <<= 1) {
            p1[r] += __shfl_xor(p1[r], off);
            p2[r] += __shfl_xor(p2[r], off);
        }
        if (lr == 0) { s1sh[w][q * 4 + r] = p1[r]; s2sh[w][q * 4 + r] = p2[r]; }
    }
    __syncthreads();
    if (tid < 16) {
        s1[r0 + tid] = s1sh[0][tid] + s1sh[1][tid] + s1sh[2][tid] + s1sh[3][tid];
        s2[r0 + tid] = s2sh[0][tid] + s2sh[1][tid] + s2sh[2][tid] + s2sh[3][tid];
    }
}

// ---------- kernel 2: fused masked-softmax @ h, f32 out ----------
// Grid 256 x 512 thr. 32 rows/block; wave w owns cols w*32..+31.
// P ring NBUF=4 (calcP 2 bodies ahead); adj/s2 LSet ring 4 ahead;
// B ring-of-4, ISSUED 2 bodies ahead (2 full bodies of flight time);
// lgkm-only barrier every 2 bodies; setprio around MFMA.
__global__ __launch_bounds__(512) void attn_kernel(
    const int* __restrict__ adj,             // 8192 x 8192 i32
    const unsigned short* __restrict__ hTt,  // tiled 256 x 8192 bf16
    const float* __restrict__ s1,
    const float* __restrict__ s2,
    float* __restrict__ out)                 // 8192 x 256 f32
{
    __shared__ unsigned short P[4][AROWS * PS];   // 34.8 KB ring
    __shared__ float dsh[AROWS];

    const int tid = threadIdx.x;
    const int r0 = blockIdx.x * AROWS;

    // P-generation role: thread -> (row, 8-col group)
    const int prow = tid >> 4;                 // 0..31
    const int pq = tid & 15;                   // cols pq*8..+7
    const float s1v = s1[r0 + prow];
    const int* arow = adj + (size_t)(r0 + prow) * NN + pq * 8;
    float denp = 0.f;

    // MFMA role
    const int w = tid >> 6, l = tid & 63, q = l >> 4, lr = l & 15;
    const int cbase = w * 32;
    fx4 acc[2][2] = {};

    struct LSet { ix4 v0, v1; fx4 s2a, s2b; };
    LSet S0, S1, S2, S3;                       // LSet ring, slot = kt & 3
    bf16x8 B0[4][2], B1[4][2], B2[4][2], B3[4][2];   // B ring, slot = it & 3

    auto loadP = [&](int kt, LSet& L) {
        const int* ap = arow + kt * 128;
        L.v0 = __builtin_nontemporal_load((const ix4*)ap);       // nt: keep the
        L.v1 = __builtin_nontemporal_load((const ix4*)(ap + 4)); // stream out of L2
        L.s2a = *(const fx4*)(s2 + kt * 128 + pq * 8);
        L.s2b = *(const fx4*)(s2 + kt * 128 + pq * 8 + 4);
    };
    auto calcP = [&](int b, const LSet& L) {   // writes P[b]
        bf16x8 pv;
#pragma unroll
        for (int j = 0; j < 8; ++j) {
            const int aj = (j < 4) ? L.v0[j] : L.v1[j - 4];
            const float s2j = (j < 4) ? L.s2a[j] : L.s2b[j - 4];
            float t = s1v + s2j;
            float e = fmaxf(t, 0.2f * t);      // leaky_relu, alpha=0.2
            e = fminf(e, 30.f);                // overflow guard (inactive)
            const float p = (aj != 0) ? __expf(e) : 0.f;
            denp += p;
            pv[j] = (short)f2bf(p);
        }
        *(bf16x8*)(&P[b][prow * PS + pq * 8]) = pv;   // 16B store
    };
    auto loadB = [&](int it, bf16x8 (&B)[4][2]) {
#pragma unroll
        for (int ks = 0; ks < 4; ++ks)
#pragma unroll
            for (int tc = 0; tc < 2; ++tc)
                B[ks][tc] = *(const bf16x8*)(hTt + ((size_t)(it * 4 + ks) * 256 + cbase + tc * 16 + lr) * 32 + q * 8);
    };

    // LDS-only barrier: ds ops drained (lgkmcnt), global loads stay in flight.
    auto ldsBarrier = [&]() {
        asm volatile("s_waitcnt lgkmcnt(0)" ::: "memory");
        __builtin_amdgcn_s_barrier();
    };

    const int ITERS = NN / 128;   // 64

    // prologue: LSets kt=0..3; B(0),B(1) in flight; P[0],P[1] written.
    loadP(0, S0); loadP(1, S1); loadP(2, S2); loadP(3, S3);
    loadB(0, B0); loadB(1, B1);
    calcP(0, S0);                 // kt=0 -> P[0]
    calcP(1, S1);                 // kt=1 -> P[1]
    ldsBarrier();

    // body j: consume B[j&3]; ISSUE loadB(j+2) into B[(j+2)&3]; read P[j&3];
    // calcP kt=j+2 -> P[(j+2)&3] (LSet loaded 4 ahead); loadP(j+4) into S[j&3].
    auto body = [&](int j, bf16x8 (&Bc)[4][2], bf16x8 (&Bi)[4][2],
                    LSet& Scons, LSet& Sload, bool bar) {
        if (j + 2 < ITERS) loadB(j + 2, Bi);       // 2 bodies of flight
        if (j + 4 < ITERS) loadP(j + 4, Sload);    // 4-deep adj/s2 stream
        const unsigned short* Pb = P[j & 3];
        bf16x8 af0[4], af1[4];
#pragma unroll
        for (int ks = 0; ks < 4; ++ks) {
            af0[ks] = *(const bf16x8*)(Pb + lr * PS + ks * 32 + q * 8);
            af1[ks] = *(const bf16x8*)(Pb + (16 + lr) * PS + ks * 32 + q * 8);
        }
        if (j + 2 < ITERS) calcP((j + 2) & 3, Scons);  // off the critical path
        __builtin_amdgcn_s_setprio(1);
#pragma unroll
        for (int ks = 0; ks < 4; ++ks)
#pragma unroll
            for (int tc = 0; tc < 2; ++tc) {
                acc[0][tc] = __builtin_amdgcn_mfma_f32_16x16x32_bf16(af0[ks], Bc[ks][tc], acc[0][tc], 0, 0, 0);
                acc[1][tc] = __builtin_amdgcn_mfma_f32_16x16x32_bf16(af1[ks], Bc[ks][tc], acc[1][tc], 0, 0, 0);
            }
        __builtin_amdgcn_s_setprio(0);
        if (bar) ldsBarrier();
    };

    for (int it = 0; it < ITERS; it += 4) {
        body(it + 0, B0, B2, S2, S0, false);   // consume B0/P[0]; issue B2; P[2] from S2; load S0=kt it+4
        body(it + 1, B1, B3, S3, S1, true);    // consume B1/P[1]; issue B3; P[3] from S3; load S1
        body(it + 2, B2, B0, S0, S2, false);   // consume B2/P[2]; issue B0; P[0] from S0; load S2
        body(it + 3, B3, B1, S1, S3, true);    // consume B3/P[3]; issue B1; P[1] from S1; load S3
    }

    // den: reduce over the 16 lanes sharing a row
    float v = denp;
    v += __shfl_xor(v, 1);
    v += __shfl_xor(v, 2);
    v += __shfl_xor(v, 4);
    v += __shfl_xor(v, 8);
    if (pq == 0) dsh[prow] = v;
    __syncthreads();

#pragma unroll
    for (int mg = 0; mg < 2; ++mg) {
#pragma unroll
        for (int r = 0; r < 4; ++r) {
            const int row = mg * 16 + q * 4 + r;
            const float dinv = 1.0f / fmaxf(dsh[row], 1e-30f);
#pragma unroll
            for (int tc = 0; tc < 2; ++tc) {
                out[(size_t)(r0 + row) * FOUT + cbase + tc * 16 + lr] = acc[mg][tc][r] * dinv;
            }
        }
    }
}

extern "C" void kernel_launch(void* const* d_in, const int* in_sizes, int n_in,
                              void* d_out, int out_size, void* d_ws, size_t ws_size,
                              hipStream_t stream) {
    const float *X = nullptr, *W = nullptr, *A = nullptr;
    const int* adj = nullptr;
    for (int i = 0; i < n_in; ++i) {
        switch (in_sizes[i]) {
            case NN * FIN:   X = (const float*)d_in[i]; break;
            case FIN * FOUT: W = (const float*)d_in[i]; break;
            case 2 * FOUT:   A = (const float*)d_in[i]; break;
            case NN * NN:    adj = (const int*)d_in[i]; break;
        }
    }
    if (!X) X = (const float*)d_in[0];
    if (!W) W = (const float*)d_in[1];
    if (!A) A = (const float*)d_in[2];
    if (!adj) adj = (const int*)d_in[3];
    float* out = (float*)d_out;

    // ws layout (subset of the 1 GiB ws):
    char* ws = (char*)d_ws;
    float* s1 = (float*)ws;                                 // 32 KB
    float* s2 = (float*)(ws + 32768);                       // 32 KB
    unsigned short* WTt = (unsigned short*)(ws + 98304);    // 256 KB
    unsigned short* hTt = (unsigned short*)(ws + 360448);   // 4 MB

    wt_kernel<<<512, 256, 0, stream>>>(W, WTt);
    prep_kernel<<<512, 256, 0, stream>>>(X, WTt, A, hTt, s1, s2);
    attn_kernel<<<NN / AROWS, 512, 0, stream>>>(adj, hTt, s1, s2, out);
}

// Round 11
// 413.315 us; speedup vs baseline: 1.3718x; 1.3718x over previous
//
#include <hip/hip_runtime.h>

// GAT layer, N=8192, F_IN=512, F_OUT=256. ALL tensors f32; adj int32.
// out = softmax_row(mask(leaky(s1_i+s2_j))) @ h, h = X@W, s{1,2} = h_f32@a{1,2}.
//
// R20 -> R21:
//  * R20: compiler clamped VGPR at 128 (launch_bounds w/o min-waves) -> 233 MB
//    spills. Fix: __launch_bounds__(512, 2) -> cap 256 VGPR, 2 waves/SIMD.
//  * R19 re-audit: its row-groups DUPLICATED B loads (chip B traffic 2 GB) ->
//    volume law confirmed, not refuted. Model: attn is L3-BW-bound on B
//    (1 GB at ~16 B/cyc/CU ~= 100us; hTt 4MB == L2 size, evicted by streams).
//  * R21 halves chip B traffic: 64 rows x 256 cols x HALF-K per block
//    (kh=bid&1, 32 bodies). B frags feed acc[4][2] (4 row-frags) -> real
//    reuse. Per-XCD hot hTt = 2 MB -> L2-resident with slack.
//  * Partial num (16 MB) + den to ws; combine kernel (~5us) sums and divides.
//  * calcP(kq)/LSet/loadB/schedule are R13/R19-proven verbatim.

typedef __attribute__((ext_vector_type(8))) short bf16x8;
typedef __attribute__((ext_vector_type(4))) float fx4;
typedef __attribute__((ext_vector_type(4))) int ix4;
typedef __attribute__((ext_vector_type(2))) unsigned int ux2;

#define NN 8192
#define FIN 512
#define FOUT 256
#define PS 136     // LDS P row stride (shorts); 272B stride -> low-conflict b128
#define AROWS 64   // attn rows per block (x half-K split)

__device__ __forceinline__ unsigned short f2bf(float f) {
    unsigned int x = __float_as_uint(f);
    x += 0x7fffu + ((x >> 16) & 1u);
    return (unsigned short)(x >> 16);
}
__device__ __forceinline__ bf16x8 pack8(fx4 a, fx4 b) {
    bf16x8 r;
    r[0] = (short)f2bf(a[0]); r[1] = (short)f2bf(a[1]);
    r[2] = (short)f2bf(a[2]); r[3] = (short)f2bf(a[3]);
    r[4] = (short)f2bf(b[0]); r[5] = (short)f2bf(b[1]);
    r[6] = (short)f2bf(b[2]); r[7] = (short)f2bf(b[3]);
    return r;
}

// ---------- kernel 0: WTt[((k>>5)*256+c)*32 + (k&31)] = bf16(W[k][c]) ----------
__global__ void wt_kernel(const float* __restrict__ W,
                          unsigned short* __restrict__ WTt) {
    const int c = threadIdx.x;
    const int k = blockIdx.x;
    WTt[((size_t)(k >> 5) * 256 + c) * 32 + (k & 31)] = f2bf(W[k * FOUT + c]);
}

// ---------- kernel 1: h-tile (MFMA) + fused s1/s2 ----------
__global__ __launch_bounds__(256) void prep_kernel(
    const float* __restrict__ X,              // 8192x512 f32
    const unsigned short* __restrict__ WTt,   // tiled 256x512 bf16
    const float* __restrict__ A,              // 512 f32 (a1|a2)
    unsigned short* __restrict__ hTt,         // tiled 256x8192 bf16
    float* __restrict__ s1, float* __restrict__ s2)
{
    __shared__ float s1sh[4][16], s2sh[4][16];
    const int tid = threadIdx.x;

    const int w = tid >> 6, l = tid & 63, q = l >> 4, lr = l & 15;
    const int r0 = blockIdx.x * 16;
    const int cbase = w * 64;
    fx4 acc[4] = {};

    for (int kb = 0; kb < FIN; kb += 32) {
        const float* xp = X + (size_t)(r0 + lr) * FIN + kb + q * 8;
        bf16x8 a0 = pack8(*(const fx4*)xp, *(const fx4*)(xp + 4));
#pragma unroll
        for (int tc = 0; tc < 4; ++tc) {
            bf16x8 b = *(const bf16x8*)(WTt + ((size_t)(kb >> 5) * 256 + cbase + tc * 16 + lr) * 32 + q * 8);
            acc[tc] = __builtin_amdgcn_mfma_f32_16x16x32_bf16(a0, b, acc[tc], 0, 0, 0);
        }
    }

    // tiled hTt write
    const int jb = r0 >> 5, jo = (r0 & 31) + q * 4;
#pragma unroll
    for (int tc = 0; tc < 4; ++tc) {
        const int c = cbase + tc * 16 + lr;
        ux2 hp;
        hp.x = (unsigned)f2bf(acc[tc][0]) | ((unsigned)f2bf(acc[tc][1]) << 16);
        hp.y = (unsigned)f2bf(acc[tc][2]) | ((unsigned)f2bf(acc[tc][3]) << 16);
        *(ux2*)(hTt + ((size_t)jb * 256 + c) * 32 + jo) = hp;
    }

    // fused s1/s2 from f32 accumulators
    float p1[4] = {}, p2[4] = {};
#pragma unroll
    for (int tc = 0; tc < 4; ++tc) {
        const int c = cbase + tc * 16 + lr;
        const float a1v = A[c], a2v = A[FOUT + c];
#pragma unroll
        for (int r = 0; r < 4; ++r) {
            p1[r] += acc[tc][r] * a1v;
            p2[r] += acc[tc][r] * a2v;
        }
    }
#pragma unroll
    for (int r = 0; r < 4; ++r) {
#pragma unroll
        for (int off = 1; off < 16; off <<= 1) {
            p1[r] += __shfl_xor(p1[r], off);
            p2[r] += __shfl_xor(p2[r], off);
        }
        if (lr == 0) { s1sh[w][q * 4 + r] = p1[r]; s2sh[w][q * 4 + r] = p2[r]; }
    }
    __syncthreads();
    if (tid < 16) {
        s1[r0 + tid] = s1sh[0][tid] + s1sh[1][tid] + s1sh[2][tid] + s1sh[3][tid];
        s2[r0 + tid] = s2sh[0][tid] + s2sh[1][tid] + s2sh[2][tid] + s2sh[3][tid];
    }
}

// ---------- kernel 2: partial masked-softmax-numerator @ h ----------
// Grid 256 x 512 thr. Block = (rg = bid>>1) rows rg*64..+63, (kh = bid&1)
// K-half kh*4096..+4095 (32 bodies of 128 k). Wave w: cols w*32..+31, ALL 64
// rows via acc[4][2] -> B frags reused 4x (chip B traffic halved to 512 MB;
// per-XCD hot hTt = 2 MB -> L2-resident). Writes partial num (f32) + den.
// P (64x128 bf16) dbuf; adj nt 2-bodies-ahead LSets; B dbuf 1 ahead;
// lgkm-only barrier per body; setprio around MFMA.
__global__ __launch_bounds__(512, 2) void attn_kernel(
    const int* __restrict__ adj,             // 8192 x 8192 i32
    const unsigned short* __restrict__ hTt,  // tiled 256 x 8192 bf16
    const float* __restrict__ s1,
    const float* __restrict__ s2,
    float* __restrict__ num,                 // 2 x 8192 x 256 f32 partial
    float* __restrict__ den)                 // 2 x 8192 f32 partial
{
    __shared__ unsigned short P[2][AROWS * PS];   // 34.8 KB
    const int tid = threadIdx.x;
    const int rg = blockIdx.x >> 1;
    const int kh = blockIdx.x & 1;             // K-half (== XCD parity)
    const int r0 = rg * AROWS;
    const int khB = kh * 32;                   // first body kt of this half

    // P-generation role: thread -> (row, 8-k slice in each 64-k half of body)
    const int prow = tid >> 3;                 // 0..63
    const int pq = tid & 7;                    // k-cols pq*8..+7 per kq-half
    const float s1v = s1[r0 + prow];
    const int* arow = adj + (size_t)(r0 + prow) * NN + (size_t)kh * 4096 + pq * 8;
    float denp = 0.f;

    // MFMA role: wave w -> cols w*32..+31, rows 0..63 (4 row-frags)
    const int w = tid >> 6, l = tid & 63, q = l >> 4, lr = l & 15;
    const int cbase = w * 32;
    fx4 acc[4][2] = {};

    struct LSet { ix4 v0, v1; fx4 s2a, s2b; };
    LSet SA, SB;                               // kq=0 / kq=1 (R19-proven dance)
    bf16x8 B0[4][2], B1[4][2];

    auto loadS = [&](int s, int kq, LSet& L) { // inputs for body s, k-quarter kq
        const int* ap = arow + s * 128 + kq * 64;
        L.v0 = __builtin_nontemporal_load((const ix4*)ap);
        L.v1 = __builtin_nontemporal_load((const ix4*)(ap + 4));
        const float* sp = s2 + (khB + s) * 128 + kq * 64 + pq * 8;
        L.s2a = *(const fx4*)sp;
        L.s2b = *(const fx4*)(sp + 4);
    };
    auto calcP = [&](int b, int kq, const LSet& L) {   // writes P[b], half kq
        bf16x8 pv;
#pragma unroll
        for (int j = 0; j < 8; ++j) {
            const int aj = (j < 4) ? L.v0[j] : L.v1[j - 4];
            const float s2j = (j < 4) ? L.s2a[j] : L.s2b[j - 4];
            float t = s1v + s2j;
            float e = fmaxf(t, 0.2f * t);      // leaky_relu, alpha=0.2
            e = fminf(e, 30.f);                // overflow guard (inactive)
            const float p = (aj != 0) ? __expf(e) : 0.f;
            denp += p;
            pv[j] = (short)f2bf(p);
        }
        *(bf16x8*)(&P[b][prow * PS + kq * 64 + pq * 8]) = pv;   // 16B store
    };
    auto loadB = [&](int s, bf16x8 (&B)[4][2]) {
        const int kt = khB + s;
#pragma unroll
        for (int ks = 0; ks < 4; ++ks)
#pragma unroll
            for (int tc = 0; tc < 2; ++tc)
                B[ks][tc] = *(const bf16x8*)(hTt + ((size_t)(kt * 4 + ks) * 256 + cbase + tc * 16 + lr) * 32 + q * 8);
    };

    // LDS-only barrier: ds ops drained (lgkmcnt), global loads stay in flight.
    auto ldsBarrier = [&]() {
        asm volatile("s_waitcnt lgkmcnt(0)" ::: "memory");
        __builtin_amdgcn_s_barrier();
    };

    const int ITERS = 32;         // bodies (128 k each) in this K-half

    loadS(0, 0, SA); loadS(0, 1, SB);
    calcP(0, 0, SA); calcP(0, 1, SB);          // P[0]
    loadS(1, 0, SA); loadS(1, 1, SB);
    loadB(0, B0);
    ldsBarrier();

    auto body = [&](int it, bf16x8 (&Bc)[4][2], bf16x8 (&Bn)[4][2]) {
        if (it + 1 < ITERS) loadB(it + 1, Bn);     // in flight across barrier
        const unsigned short* Pb = P[it & 1];
#pragma unroll
        for (int rg4 = 0; rg4 < 4; ++rg4) {        // 4 row-frags reuse Bc
            bf16x8 af[4];
#pragma unroll
            for (int ks = 0; ks < 4; ++ks)
                af[ks] = *(const bf16x8*)(Pb + (rg4 * 16 + lr) * PS + ks * 32 + q * 8);
            __builtin_amdgcn_s_setprio(1);
#pragma unroll
            for (int ks = 0; ks < 4; ++ks)
#pragma unroll
                for (int tc = 0; tc < 2; ++tc)
                    acc[rg4][tc] = __builtin_amdgcn_mfma_f32_16x16x32_bf16(af[ks], Bc[ks][tc], acc[rg4][tc], 0, 0, 0);
            __builtin_amdgcn_s_setprio(0);
        }
        if (it + 1 < ITERS) {
            calcP((it + 1) & 1, 0, SA);            // consume (loaded last body)
            calcP((it + 1) & 1, 1, SB);
        }
        if (it + 2 < ITERS) {
            loadS(it + 2, 0, SA);                  // refill for next body
            loadS(it + 2, 1, SB);
        }
        ldsBarrier();
    };

    for (int it = 0; it < ITERS; it += 2) {
        body(it, B0, B1);
        body(it + 1, B1, B0);
    }

    // partial den: reduce over the 8 lanes sharing a row
    float v = denp;
    v += __shfl_xor(v, 1);
    v += __shfl_xor(v, 2);
    v += __shfl_xor(v, 4);
    if (pq == 0) den[(size_t)kh * NN + r0 + prow] = v;

    // partial num: raw f32 accumulators
    float* nb = num + (size_t)kh * NN * FOUT;
#pragma unroll
    for (int rg4 = 0; rg4 < 4; ++rg4)
#pragma unroll
        for (int r = 0; r < 4; ++r) {
            const int row = rg4 * 16 + q * 4 + r;
#pragma unroll
            for (int tc = 0; tc < 2; ++tc)
                nb[(size_t)(r0 + row) * FOUT + cbase + tc * 16 + lr] = acc[rg4][tc][r];
        }
}

// ---------- kernel 3: combine K-half partials, divide by total den ----------
// 1024 blocks x 512 thr; one fx4 (4 cols of one row) per thread.
__global__ __launch_bounds__(512) void combine_kernel(
    const float* __restrict__ num, const float* __restrict__ den,
    float* __restrict__ out)
{
    const int idx = blockIdx.x * 512 + threadIdx.x;   // fx4 index, 524288 total
    const int r = idx >> 6;                           // 64 fx4 per 256-col row
    const fx4 a = *(const fx4*)(num + (size_t)idx * 4);
    const fx4 b = *(const fx4*)(num + (size_t)NN * FOUT + (size_t)idx * 4);
    const float dinv = 1.0f / fmaxf(den[r] + den[NN + r], 1e-30f);
    fx4 o;
#pragma unroll
    for (int j = 0; j < 4; ++j) o[j] = (a[j] + b[j]) * dinv;
    *(fx4*)(out + (size_t)idx * 4) = o;
}

extern "C" void kernel_launch(void* const* d_in, const int* in_sizes, int n_in,
                              void* d_out, int out_size, void* d_ws, size_t ws_size,
                              hipStream_t stream) {
    const float *X = nullptr, *W = nullptr, *A = nullptr;
    const int* adj = nullptr;
    for (int i = 0; i < n_in; ++i) {
        switch (in_sizes[i]) {
            case NN * FIN:   X = (const float*)d_in[i]; break;
            case FIN * FOUT: W = (const float*)d_in[i]; break;
            case 2 * FOUT:   A = (const float*)d_in[i]; break;
            case NN * NN:    adj = (const int*)d_in[i]; break;
        }
    }
    if (!X) X = (const float*)d_in[0];
    if (!W) W = (const float*)d_in[1];
    if (!A) A = (const float*)d_in[2];
    if (!adj) adj = (const int*)d_in[3];
    float* out = (float*)d_out;

    // ws layout (~26 MB of the 1 GiB ws):
    char* ws = (char*)d_ws;
    float* s1 = (float*)ws;                                 // 32 KB
    float* s2 = (float*)(ws + 32768);                       // 32 KB
    unsigned short* WTt = (unsigned short*)(ws + 98304);    // 256 KB
    unsigned short* hTt = (unsigned short*)(ws + 360448);   // 4 MB
    float* num = (float*)(ws + 8388608);                    // 2 x 8 MB partials
    float* den = (float*)(ws + 25165824);                   // 64 KB partials

    wt_kernel<<<512, 256, 0, stream>>>(W, WTt);
    prep_kernel<<<512, 256, 0, stream>>>(X, WTt, A, hTt, s1, s2);
    attn_kernel<<<(NN / AROWS) * 2, 512, 0, stream>>>(adj, hTt, s1, s2, num, den);
    combine_kernel<<<1024, 512, 0, stream>>>(num, den, out);
}

// Round 13
// 409.194 us; speedup vs baseline: 1.3856x; 1.0101x over previous
//
#include <hip/hip_runtime.h>

// GAT layer, N=8192, F_IN=512, F_OUT=256. ALL tensors f32; adj int32.
// out = softmax_row(mask(leaky(s1_i+s2_j))) @ h, h = X@W, s{1,2} = h_f32@a{1,2}.
//
// R22 -> R23:
//  * R22 crashed: combine_kernel launched with 4096 blocks instead of 1024
//    (524288 fx4 total) -> out-of-bounds writes on the 8 MB output. Fixed
//    grid; attn kernel unchanged (audited, untested).
//  * Theory (from R21's confirmed B-volume law): 128 rows x 256 cols x
//    QUARTER-K per block (kq=bid&3, 16 bodies). Chip B traffic 512->256 MB;
//    per-XCD hot hTt = 1 MB (XCD=bid&7 fixes bid&3) -> deep L2 residency.
//  * P single-buffered [128][136] (34.8 KB, 2 barriers/body; R15 proved
//    decoupling worth ~0). B single-buffered (covered by calcP phase).
//    adj-only register prefetch 1 body ahead; s2 batch-loaded per phase A.
//  * VGPR ~200 under (512,2) cap 256 -> no spill (canary: attn WRITE_SIZE
//    ~= 33 MB partials, not hundreds).

typedef __attribute__((ext_vector_type(8))) short bf16x8;
typedef __attribute__((ext_vector_type(4))) float fx4;
typedef __attribute__((ext_vector_type(4))) int ix4;
typedef __attribute__((ext_vector_type(2))) unsigned int ux2;

#define NN 8192
#define FIN 512
#define FOUT 256
#define PS 136     // LDS P row stride (shorts); 272B stride -> low-conflict b128
#define AROWS 128  // attn rows per block (x quarter-K split)

__device__ __forceinline__ unsigned short f2bf(float f) {
    unsigned int x = __float_as_uint(f);
    x += 0x7fffu + ((x >> 16) & 1u);
    return (unsigned short)(x >> 16);
}
__device__ __forceinline__ bf16x8 pack8(fx4 a, fx4 b) {
    bf16x8 r;
    r[0] = (short)f2bf(a[0]); r[1] = (short)f2bf(a[1]);
    r[2] = (short)f2bf(a[2]); r[3] = (short)f2bf(a[3]);
    r[4] = (short)f2bf(b[0]); r[5] = (short)f2bf(b[1]);
    r[6] = (short)f2bf(b[2]); r[7] = (short)f2bf(b[3]);
    return r;
}

// ---------- kernel 0: WTt[((k>>5)*256+c)*32 + (k&31)] = bf16(W[k][c]) ----------
__global__ void wt_kernel(const float* __restrict__ W,
                          unsigned short* __restrict__ WTt) {
    const int c = threadIdx.x;
    const int k = blockIdx.x;
    WTt[((size_t)(k >> 5) * 256 + c) * 32 + (k & 31)] = f2bf(W[k * FOUT + c]);
}

// ---------- kernel 1: h-tile (MFMA) + fused s1/s2 ----------
__global__ __launch_bounds__(256) void prep_kernel(
    const float* __restrict__ X,              // 8192x512 f32
    const unsigned short* __restrict__ WTt,   // tiled 256x512 bf16
    const float* __restrict__ A,              // 512 f32 (a1|a2)
    unsigned short* __restrict__ hTt,         // tiled 256x8192 bf16
    float* __restrict__ s1, float* __restrict__ s2)
{
    __shared__ float s1sh[4][16], s2sh[4][16];
    const int tid = threadIdx.x;

    const int w = tid >> 6, l = tid & 63, q = l >> 4, lr = l & 15;
    const int r0 = blockIdx.x * 16;
    const int cbase = w * 64;
    fx4 acc[4] = {};

    for (int kb = 0; kb < FIN; kb += 32) {
        const float* xp = X + (size_t)(r0 + lr) * FIN + kb + q * 8;
        bf16x8 a0 = pack8(*(const fx4*)xp, *(const fx4*)(xp + 4));
#pragma unroll
        for (int tc = 0; tc < 4; ++tc) {
            bf16x8 b = *(const bf16x8*)(WTt + ((size_t)(kb >> 5) * 256 + cbase + tc * 16 + lr) * 32 + q * 8);
            acc[tc] = __builtin_amdgcn_mfma_f32_16x16x32_bf16(a0, b, acc[tc], 0, 0, 0);
        }
    }

    // tiled hTt write
    const int jb = r0 >> 5, jo = (r0 & 31) + q * 4;
#pragma unroll
    for (int tc = 0; tc < 4; ++tc) {
        const int c = cbase + tc * 16 + lr;
        ux2 hp;
        hp.x = (unsigned)f2bf(acc[tc][0]) | ((unsigned)f2bf(acc[tc][1]) << 16);
        hp.y = (unsigned)f2bf(acc[tc][2]) | ((unsigned)f2bf(acc[tc][3]) << 16);
        *(ux2*)(hTt + ((size_t)jb * 256 + c) * 32 + jo) = hp;
    }

    // fused s1/s2 from f32 accumulators
    float p1[4] = {}, p2[4] = {};
#pragma unroll
    for (int tc = 0; tc < 4; ++tc) {
        const int c = cbase + tc * 16 + lr;
        const float a1v = A[c], a2v = A[FOUT + c];
#pragma unroll
        for (int r = 0; r < 4; ++r) {
            p1[r] += acc[tc][r] * a1v;
            p2[r] += acc[tc][r] * a2v;
        }
    }
#pragma unroll
    for (int r = 0; r < 4; ++r) {
#pragma unroll
        for (int off = 1; off < 16; off <<= 1) {
            p1[r] += __shfl_xor(p1[r], off);
            p2[r] += __shfl_xor(p2[r], off);
        }
        if (lr == 0) { s1sh[w][q * 4 + r] = p1[r]; s2sh[w][q * 4 + r] = p2[r]; }
    }
    __syncthreads();
    if (tid < 16) {
        s1[r0 + tid] = s1sh[0][tid] + s1sh[1][tid] + s1sh[2][tid] + s1sh[3][tid];
        s2[r0 + tid] = s2sh[0][tid] + s2sh[1][tid] + s2sh[2][tid] + s2sh[3][tid];
    }
}

// ---------- kernel 2: partial masked-softmax-numerator @ h ----------
// Grid 256 x 512 thr. Block = (rg = bid>>2) rows rg*128..+127, (kq = bid&3)
// K-quarter kq*2048..+2047 (16 bodies of 128 k). Wave w: cols w*32..+31,
// ALL 128 rows via acc[8][2] -> B reused 8x. Per body: phase A = calcP
// (adj prefetched 1 body ahead in regs; s2 batch; B loads issued at top,
// covered by calcP VALU) -> barrier -> phase B = 8x(af ds_read + 8 MFMA)
// -> barrier. Writes partial num (f32) + den per K-quarter.
__global__ __launch_bounds__(512, 2) void attn_kernel(
    const int* __restrict__ adj,             // 8192 x 8192 i32
    const unsigned short* __restrict__ hTt,  // tiled 256 x 8192 bf16
    const float* __restrict__ s1,
    const float* __restrict__ s2,
    float* __restrict__ num,                 // 4 x 8192 x 256 f32 partial
    float* __restrict__ den)                 // 4 x 8192 f32 partial
{
    __shared__ unsigned short P[AROWS * PS];   // 34.8 KB single buffer

    const int tid = threadIdx.x;
    const int rg = blockIdx.x >> 2;
    const int kq = blockIdx.x & 3;             // K-quarter (XCD-aligned)
    const int r0 = rg * AROWS;
    const int kb0 = kq * 16;                   // first 128k-tile of this quarter

    // P-generation role: thread -> (row, 8-k slice per 32-k group)
    const int prow = tid >> 2;                 // 0..127
    const int pq = tid & 3;                    // k = j8*32 + pq*8
    const float s1v = s1[r0 + prow];
    const int* arow = adj + (size_t)(r0 + prow) * NN + kq * 2048 + pq * 8;
    float denp = 0.f;

    // MFMA role: wave w -> cols w*32..+31, rows 0..127 (8 row-frags)
    const int w = tid >> 6, l = tid & 63, q = l >> 4, lr = l & 15;
    const int cbase = w * 32;
    fx4 acc[8][2] = {};

    ix4 av[8];                                 // adj for current body (4 j8 x 2)
    bf16x8 B[4][2];                            // single-buffered B

    auto loadA = [&](int it) {                 // adj for body it -> av
        const int* ap = arow + it * 128;
#pragma unroll
        for (int j8 = 0; j8 < 4; ++j8) {
            av[2 * j8]     = __builtin_nontemporal_load((const ix4*)(ap + j8 * 32));
            av[2 * j8 + 1] = __builtin_nontemporal_load((const ix4*)(ap + j8 * 32 + 4));
        }
    };
    auto loadB = [&](int it) {
        const int kt = kb0 + it;
#pragma unroll
        for (int ks = 0; ks < 4; ++ks)
#pragma unroll
            for (int tc = 0; tc < 2; ++tc)
                B[ks][tc] = *(const bf16x8*)(hTt + ((size_t)(kt * 4 + ks) * 256 + cbase + tc * 16 + lr) * 32 + q * 8);
    };
    auto phaseA = [&](int it) {                // consumes av, writes P
        fx4 s2v[8];
        const float* sp = s2 + (kb0 + it) * 128 + pq * 8;
#pragma unroll
        for (int j8 = 0; j8 < 4; ++j8) {
            s2v[2 * j8]     = *(const fx4*)(sp + j8 * 32);
            s2v[2 * j8 + 1] = *(const fx4*)(sp + j8 * 32 + 4);
        }
#pragma unroll
        for (int j8 = 0; j8 < 4; ++j8) {
            bf16x8 pv;
#pragma unroll
            for (int j = 0; j < 8; ++j) {
                const int aj = (j < 4) ? av[2 * j8][j] : av[2 * j8 + 1][j - 4];
                const float s2j = (j < 4) ? s2v[2 * j8][j] : s2v[2 * j8 + 1][j - 4];
                float t = s1v + s2j;
                float e = fmaxf(t, 0.2f * t);  // leaky_relu, alpha=0.2
                e = fminf(e, 30.f);            // overflow guard (inactive)
                const float p = (aj != 0) ? __expf(e) : 0.f;
                denp += p;
                pv[j] = (short)f2bf(p);
            }
            *(bf16x8*)(&P[prow * PS + j8 * 32 + pq * 8]) = pv;   // 16B store
        }
    };
    auto ldsBarrier = [&]() {
        asm volatile("s_waitcnt lgkmcnt(0)" ::: "memory");
        __builtin_amdgcn_s_barrier();
    };

    const int ITERS = 16;         // bodies (128 k each) in this K-quarter

    loadA(0);
    for (int it = 0; it < ITERS; ++it) {
        loadB(it);                             // covered by phase A VALU
        phaseA(it);                            // consumes av, writes P
        if (it + 1 < ITERS) loadA(it + 1);     // refill av (1 body of flight)
        ldsBarrier();                          // P visible; B/adj in flight
#pragma unroll
        for (int rg8 = 0; rg8 < 8; ++rg8) {    // 8 row-frags reuse B
            bf16x8 af[4];
#pragma unroll
            for (int ks = 0; ks < 4; ++ks)
                af[ks] = *(const bf16x8*)(&P[(rg8 * 16 + lr) * PS + ks * 32 + q * 8]);
            __builtin_amdgcn_s_setprio(1);
#pragma unroll
            for (int ks = 0; ks < 4; ++ks)
#pragma unroll
                for (int tc = 0; tc < 2; ++tc)
                    acc[rg8][tc] = __builtin_amdgcn_mfma_f32_16x16x32_bf16(af[ks], B[ks][tc], acc[rg8][tc], 0, 0, 0);
            __builtin_amdgcn_s_setprio(0);
        }
        ldsBarrier();                          // P consumed -> safe to overwrite
    }

    // partial den: reduce over the 4 lanes sharing a row
    float v = denp;
    v += __shfl_xor(v, 1);
    v += __shfl_xor(v, 2);
    if (pq == 0) den[(size_t)kq * NN + r0 + prow] = v;

    // partial num: raw f32 accumulators
    float* nb = num + (size_t)kq * NN * FOUT;
#pragma unroll
    for (int rg8 = 0; rg8 < 8; ++rg8)
#pragma unroll
        for (int r = 0; r < 4; ++r) {
            const int row = rg8 * 16 + q * 4 + r;
#pragma unroll
            for (int tc = 0; tc < 2; ++tc)
                nb[(size_t)(r0 + row) * FOUT + cbase + tc * 16 + lr] = acc[rg8][tc][r];
        }
}

// ---------- kernel 3: combine K-quarter partials, divide by total den ----------
// 1024 blocks x 512 thr = 524288 threads; one fx4 (4 cols of one row) each.
__global__ __launch_bounds__(512) void combine_kernel(
    const float* __restrict__ num, const float* __restrict__ den,
    float* __restrict__ out)
{
    const size_t NF = (size_t)NN * FOUT;
    const int idx = blockIdx.x * 512 + threadIdx.x;   // fx4 index, 524288 total
    const int r = idx >> 6;                           // 64 fx4 per 256-col row
    const fx4 a = *(const fx4*)(num + (size_t)idx * 4);
    const fx4 b = *(const fx4*)(num + NF + (size_t)idx * 4);
    const fx4 c = *(const fx4*)(num + 2 * NF + (size_t)idx * 4);
    const fx4 d = *(const fx4*)(num + 3 * NF + (size_t)idx * 4);
    const float dt = den[r] + den[NN + r] + den[2 * NN + r] + den[3 * NN + r];
    const float dinv = 1.0f / fmaxf(dt, 1e-30f);
    fx4 o;
#pragma unroll
    for (int j = 0; j < 4; ++j) o[j] = (a[j] + b[j] + c[j] + d[j]) * dinv;
    *(fx4*)(out + (size_t)idx * 4) = o;
}

extern "C" void kernel_launch(void* const* d_in, const int* in_sizes, int n_in,
                              void* d_out, int out_size, void* d_ws, size_t ws_size,
                              hipStream_t stream) {
    const float *X = nullptr, *W = nullptr, *A = nullptr;
    const int* adj = nullptr;
    for (int i = 0; i < n_in; ++i) {
        switch (in_sizes[i]) {
            case NN * FIN:   X = (const float*)d_in[i]; break;
            case FIN * FOUT: W = (const float*)d_in[i]; break;
            case 2 * FOUT:   A = (const float*)d_in[i]; break;
            case NN * NN:    adj = (const int*)d_in[i]; break;
        }
    }
    if (!X) X = (const float*)d_in[0];
    if (!W) W = (const float*)d_in[1];
    if (!A) A = (const float*)d_in[2];
    if (!adj) adj = (const int*)d_in[3];
    float* out = (float*)d_out;

    // ws layout (~42 MB of the 1 GiB ws):
    char* ws = (char*)d_ws;
    float* s1 = (float*)ws;                                 // 32 KB
    float* s2 = (float*)(ws + 32768);                       // 32 KB
    unsigned short* WTt = (unsigned short*)(ws + 98304);    // 256 KB
    unsigned short* hTt = (unsigned short*)(ws + 360448);   // 4 MB
    float* num = (float*)(ws + 8388608);                    // 4 x 8 MB partials
    float* den = (float*)(ws + 41943040);                   // 4 x 32 KB partials

    wt_kernel<<<512, 256, 0, stream>>>(W, WTt);
    prep_kernel<<<512, 256, 0, stream>>>(X, WTt, A, hTt, s1, s2);
    attn_kernel<<<(NN / AROWS) * 4, 512, 0, stream>>>(adj, hTt, s1, s2, num, den);
    combine_kernel<<<1024, 512, 0, stream>>>(num, den, out);
}